// Round 11
// baseline (191.792 us; speedup 1.0000x reference)
//
#include <hip/hip_runtime.h>

// MHA: B=2, S=2048, D=1024, H=16, Kd=64.
// Pipeline: detect dtype -> cast (weights transposed) to bf16 -> QKV GEMM (BK=32
// double-buffered DMA, vmcnt(4)) -> flash attention -> out GEMM.
// MFMA layouts (HW-verified): A[m=lane&15][k=(lane>>4)*8+j], B[k=(lane>>4)*8+j][n=lane&15],
// C/D: row=(lane>>4)*4+reg, col=lane&15.
// R10: cvt_pk packing + setprio. R11: permlane P^T exchange (no Plds).
// R12/R14/R15/R17: FAILED flash restructures. R13: XCD pinning (kept).
// R19: qkv panel-pinned XCD swizzle (kept; 187.19us best measured).
// R20: BARRIER-FREE flash. Diagnosis across R12-R17: limiter is inter-wave
//   barrier lockstep (pipes <45% at any occupancy/buffering; removing staging
//   (R17) fatal). Fix: per-wave private staging. Each wave owns a 16 KB LDS
//   slice (2-buf x (4KB K + 4KB V)), stages its OWN 32-key tiles with its own
//   8 DMAs + per-wave vmcnt(8). ZERO __syncthreads. WAR safety: a buffer is
//   overwritten one full SELF-iteration after the same wave's lgkm-drained
//   reads (per-wave program order, no cross-wave sharing). 8 waves/CU
//   free-run -> natural MFMA/VALU anti-phase. Costs: 4x L2 K/V re-reads
//   (~10 TB/s agg, under 34.5 ceiling), V-read 4-way bank conflict (4/12
//   reads), 4x DMA issue count. Per-key math bit-equivalent.

typedef __attribute__((ext_vector_type(8))) short short8;
typedef __attribute__((ext_vector_type(4))) float f32x4;

#define M_ROWS 4096   // B*S
#define N_COLS 1024   // H*Kd
#define K_DIM  1024   // D
#define SEQ    2048

// Q pre-scale: (1/sqrt(64)) * log2(e) so softmax exps become exp2.
#define QSCALE 0.18033688011111772f

#if defined(__has_builtin)
#if __has_builtin(__builtin_amdgcn_exp2f)
#define EXP2(x) __builtin_amdgcn_exp2f(x)
#endif
#endif
#ifndef EXP2
#define EXP2(x) exp2f(x)
#endif

// s_waitcnt immediate: vmcnt[3:0]=bits3:0, expcnt=bits6:4 (7=nowait),
// lgkmcnt=bits11:8 (0xF=nowait), vmcnt[5:4]=bits15:14.
#define WAITCNT_VM8 0x0F78
#define WAITCNT_VM4 0x0F74

__device__ inline unsigned short f2bf(float f) {
  unsigned int u = __float_as_uint(f);
  u += 0x7fffu + ((u >> 16) & 1u);   // round-to-nearest-even
  return (unsigned short)(u >> 16);
}

// HW packed f32->bf16 (RNE), 1 VALU op for 2 values (no builtin on gfx950).
__device__ inline unsigned int cvtpk(float lo, float hi) {
  unsigned int r;
  asm("v_cvt_pk_bf16_f32 %0, %1, %2" : "=v"(r) : "v"(lo), "v"(hi));
  return r;
}

// gfx950 cross-lane swaps (VALU, no LDS pipe).
// permlane32: rows(16-lane) after: a=(a0,a1,b0,b1), b=(a2,a3,b2,b3)
// permlane16: a=(a0,b0,a2,b2), b=(a1,b1,a3,b3)
__device__ inline void swap32(unsigned int& a, unsigned int& b) {
  asm("v_permlane32_swap_b32 %0, %1" : "+v"(a), "+v"(b));
}
__device__ inline void swap16(unsigned int& a, unsigned int& b) {
  asm("v_permlane16_swap_b32 %0, %1" : "+v"(a), "+v"(b));
}

// async global->LDS DMA, 16B per lane. lptr must be wave-uniform (lane i lands
// at lptr + i*16 -- m104/m108); gptr is per-lane.
__device__ inline void async_load16(const unsigned short* gptr, unsigned short* lptr) {
  __builtin_amdgcn_global_load_lds(
      (const __attribute__((address_space(1))) unsigned int*)gptr,
      (__attribute__((address_space(3))) unsigned int*)lptr, 16, 0, 0);
}

// ---------- dtype detector: flag=1 if input buffers are bf16, 0 if f32 ----------
__global__ void detect_kernel(const unsigned short* __restrict__ x, int* __restrict__ flag) {
  __shared__ int bad;
  if (threadIdx.x == 0) bad = 0;
  __syncthreads();
  for (int i = threadIdx.x; i < 1024; i += 256) {
    float f = __uint_as_float((unsigned int)x[i] << 16);
    float a = fabsf(f);
    if (!(a < 1e4f)) atomicOr(&bad, 1);   // catches huge + NaN/Inf -> really f32 data
  }
  __syncthreads();
  if (threadIdx.x == 0) *flag = bad ? 0 : 1;
}

// ---------- cast x (f32 or bf16 per flag) to canonical bf16, layout kept ----------
__global__ void convert_kernel(const void* __restrict__ src, unsigned short* __restrict__ dst,
                               int n4, const int* __restrict__ flag) {
  const int isbf = *flag;
  const int stride = gridDim.x * blockDim.x;
  for (int i = blockIdx.x * blockDim.x + threadIdx.x; i < n4; i += stride) {
    if (isbf) {
      ((uint2*)dst)[i] = ((const uint2*)src)[i];
    } else {
      float4 v = ((const float4*)src)[i];
      ushort4 o;
      o.x = f2bf(v.x); o.y = f2bf(v.y); o.z = f2bf(v.z); o.w = f2bf(v.w);
      ((ushort4*)dst)[i] = o;
    }
  }
}

// ---------- cast + transpose 4 weights [1024][1024] -> W^T bf16 [n][k] ----------
__global__ __launch_bounds__(256) void convert_wT4_kernel(
    const void* __restrict__ s0, const void* __restrict__ s1,
    const void* __restrict__ s2, const void* __restrict__ s3,
    unsigned short* __restrict__ d0, unsigned short* __restrict__ d1,
    unsigned short* __restrict__ d2, unsigned short* __restrict__ d3,
    const int* __restrict__ flag) {
  __shared__ unsigned short t[32][33];
  const int z = blockIdx.z;
  const void* src = (z == 0) ? s0 : (z == 1) ? s1 : (z == 2) ? s2 : s3;
  unsigned short* dst = (z == 0) ? d0 : (z == 1) ? d1 : (z == 2) ? d2 : d3;
  const int tid = threadIdx.x;
  const int r0 = blockIdx.y * 32, c0 = blockIdx.x * 32;   // r0: k rows, c0: n cols
  const int kr = tid >> 3, nc = (tid & 7) * 4;
  if (*flag) {
    const unsigned short* W = (const unsigned short*)src;
    uint2 v = *(const uint2*)(W + (size_t)(r0 + kr) * K_DIM + c0 + nc);
    t[kr][nc] = v.x & 0xffff; t[kr][nc + 1] = v.x >> 16;
    t[kr][nc + 2] = v.y & 0xffff; t[kr][nc + 3] = v.y >> 16;
  } else {
    const float* W = (const float*)src;
    float4 v = *(const float4*)(W + (size_t)(r0 + kr) * K_DIM + c0 + nc);
    t[kr][nc] = f2bf(v.x); t[kr][nc + 1] = f2bf(v.y);
    t[kr][nc + 2] = f2bf(v.z); t[kr][nc + 3] = f2bf(v.w);
  }
  __syncthreads();
  const int nr = tid >> 3, kc = (tid & 7) * 4;
  uint2 w;
  w.x = (unsigned int)t[kc][nr] | ((unsigned int)t[kc + 1][nr] << 16);
  w.y = (unsigned int)t[kc + 2][nr] | ((unsigned int)t[kc + 3][nr] << 16);
  *(uint2*)(dst + (size_t)(c0 + nr) * K_DIM + r0 + kc) = w;
}

// ---------- 128x128xBK32 GEMM core, double-buffered DMA + vmcnt(4) ----------
// (R9-proven form.) Per K-iter: prefetch next tile's 4 DMAs FIRST, wait
// vmcnt(4), barrier, 8 ds_read_b128 + 16 MFMA, barrier. XOR swizzle
// c = g ^ ((row^(row>>2))&3) -> 2 lanes/bank reads (free).
#define GEMM_DMA(Aptr, Bptr, KTOT, KB, BUF)                                       \
  _Pragma("unroll") for (int r = 0; r < 2; ++r) {                                 \
    int s = r * 256 + wave * 64 + lane;                                           \
    int row = s >> 2, c = s & 3;                                                  \
    int g = c ^ ((row ^ (row >> 2)) & 3);                                         \
    async_load16((Aptr) + (size_t)(m0 + row) * (KTOT) + (KB) + g * 8,             \
                 &As[BUF][(size_t)(r * 256 + wave * 64) * 8]);                    \
    async_load16((Bptr) + (size_t)(n0 + row) * (KTOT) + (KB) + g * 8,             \
                 &Bs[BUF][(size_t)(r * 256 + wave * 64) * 8]);                    \
  }

#define GEMM_MAIN_LOOP(Aptr, Bptr, KTOT)                                          \
  f32x4 acc[4][4];                                                                \
  _Pragma("unroll") for (int i = 0; i < 4; ++i)                                   \
  _Pragma("unroll") for (int j = 0; j < 4; ++j)                                   \
      acc[i][j] = (f32x4){0.f, 0.f, 0.f, 0.f};                                    \
  const int xr = (l15 ^ (l15 >> 2)) & 3;                                          \
  GEMM_DMA(Aptr, Bptr, KTOT, 0, 0)                                                \
  for (int kb = 0; kb < (KTOT); kb += 32) {                                       \
    const int pp = (kb >> 5) & 1;                                                 \
    const int kbn = (kb + 32) & ((KTOT) - 1);                                     \
    GEMM_DMA(Aptr, Bptr, KTOT, kbn, pp ^ 1)                                       \
    __builtin_amdgcn_s_waitcnt(WAITCNT_VM4);                                      \
    __syncthreads();                                                              \
    short8 am[4], bn[4];                                                          \
    _Pragma("unroll") for (int i = 0; i < 4; ++i) {                               \
      int arow = wr * 64 + i * 16 + l15;                                          \
      int brow = wc * 64 + i * 16 + l15;                                          \
      int cc = quad ^ xr;                                                         \
      am[i] = *(const short8*)(&As[pp][arow * 32 + cc * 8]);                      \
      bn[i] = *(const short8*)(&Bs[pp][brow * 32 + cc * 8]);                      \
    }                                                                             \
    _Pragma("unroll") for (int i = 0; i < 4; ++i)                                 \
    _Pragma("unroll") for (int j = 0; j < 4; ++j)                                 \
        acc[i][j] = __builtin_amdgcn_mfma_f32_16x16x32_bf16(am[i], bn[j],         \
                                                            acc[i][j], 0, 0, 0); \
    __syncthreads();                                                              \
  }

// ---------- fused QKV projection: X[4096x1024] @ W^T -> Q/K/V ----------
// R19: 1-D grid of 768, panel-pinned XCD decode: y = gid&7 (XCD = gid%8),
// wsel = (gid>>3)/32, x = (gid>>3)&31. 768 KB B working set per XCD.
__global__ __launch_bounds__(256, 3) void qkv_gemm_kernel(
    const unsigned short* __restrict__ Xb,
    const unsigned short* __restrict__ Wqt,
    const unsigned short* __restrict__ Wkt,
    const unsigned short* __restrict__ Wvt,
    unsigned short* __restrict__ Qb,
    unsigned short* __restrict__ Kb,
    unsigned short* __restrict__ Vt) {
  __shared__ __align__(16) unsigned short As[2][128 * 32];   // 2 x 8 KB
  __shared__ __align__(16) unsigned short Bs[2][128 * 32];   // 2 x 8 KB
  const int tid = threadIdx.x;
  const int wave = tid >> 6, lane = tid & 63;
  const int quad = lane >> 4, l15 = lane & 15;
  const int wr = wave >> 1, wc = wave & 1;
  const int gid = blockIdx.x;
  const int ny = gid & 7;            // XCD-pinned n-panel
  const int q = gid >> 3;
  const int wsel = q >> 5;           // 0..2
  const int m0 = (q & 31) * 128;
  const int n0 = ny * 128;
  const unsigned short* __restrict__ Bt =
      (wsel == 0) ? Wqt : ((wsel == 1) ? Wkt : Wvt);

  GEMM_MAIN_LOOP(Xb, Bt, K_DIM)

#pragma unroll
  for (int i = 0; i < 4; ++i) {
#pragma unroll
    for (int j = 0; j < 4; ++j) {
      int mbase = m0 + wr * 64 + i * 16 + quad * 4;
      int n = n0 + wc * 64 + j * 16 + l15;
      int h = n >> 6, d = n & 63;
      if (wsel == 2) {
        int b_ = mbase >> 11, s = mbase & 2047;
        uint2 w;
        w.x = cvtpk(acc[i][j][0], acc[i][j][1]);
        w.y = cvtpk(acc[i][j][2], acc[i][j][3]);
        *(uint2*)(Vt + ((size_t)(b_ * 16 + h) * 64 + d) * SEQ + s) = w;
      } else {
#pragma unroll
        for (int r = 0; r < 4; ++r) {
          int m = mbase + r;
          int b_ = m >> 11, s = m & 2047;
          float val = acc[i][j][r];
          if (wsel == 0)
            Qb[((size_t)(b_ * 16 + h) * SEQ + s) * 64 + d] = f2bf(val * QSCALE);
          else
            Kb[((size_t)(b_ * 16 + h) * SEQ + s) * 64 + d] = f2bf(val);
        }
      }
    }
  }
}

// ---------- flash attention R20: barrier-free, per-wave private staging ----------
// 512 blocks 1-D, bh = gid&31 (XCD pinning). Each wave: 32 q-rows, its own
// 16 KB LDS slice (2 bufs x (K 32x64 + V 64x32)), 64 iterations of 32-key
// tiles. Per iter: issue 8 DMAs for next tile into the OTHER buffer, per-wave
// vmcnt(8) drains current tile, compute (4 K-reads, 8 QK MFMA, softmax,
// 4 V-reads, 8 PV MFMA). No __syncthreads anywhere. WAR: buffer overwritten
// one full self-iteration after this wave's lgkm-drained reads.
__global__ __launch_bounds__(256, 2) void flash_kernel(
    const unsigned short* __restrict__ Qb,
    const unsigned short* __restrict__ Kb,
    const unsigned short* __restrict__ Vt,
    unsigned short* __restrict__ Ob) {
  __shared__ __align__(16) unsigned short Klds[4][2][32 * 64];   // per-wave 2-buf K, 32 KB
  __shared__ __align__(16) unsigned short Vlds[4][2][64 * 32];   // per-wave 2-buf V, 32 KB
  const int tid = threadIdx.x;
  const int wave = tid >> 6, lane = tid & 63;
  const int quad = lane >> 4, l15 = lane & 15;
  const int gid = blockIdx.x;
  const int bh = gid & 31;          // XCD = gid % 8 = bh % 8: head pinned to XCD
  const int qidx = gid >> 5;        // 16 q-chunks per head
  const int qbase = qidx * 128 + wave * 32;

  const unsigned short* __restrict__ Qp = Qb + (size_t)bh * SEQ * 64;
  const unsigned short* __restrict__ Kp = Kb + (size_t)bh * SEQ * 64;
  const unsigned short* __restrict__ Vp = Vt + (size_t)bh * 64 * SEQ;

  unsigned short* const Kl0 = &Klds[wave][0][0];
  unsigned short* const Kl1 = &Klds[wave][1][0];
  unsigned short* const Vl0 = &Vlds[wave][0][0];
  unsigned short* const Vl1 = &Vlds[wave][1][0];

  short8 qf[2][2];
#pragma unroll
  for (int g = 0; g < 2; ++g)
#pragma unroll
    for (int h = 0; h < 2; ++h)
      qf[g][h] = *(const short8*)(Qp + (size_t)(qbase + g * 16 + l15) * 64 + h * 32 + quad * 8);

  f32x4 O[2][4];
#pragma unroll
  for (int g = 0; g < 2; ++g)
#pragma unroll
    for (int t = 0; t < 4; ++t) O[g][t] = (f32x4){0.f, 0.f, 0.f, 0.f};
  float l_i[2] = {0.f, 0.f};   // per-lane partials; cross-lane reduce at epilogue

  // Per-wave DMA of one 32-key tile: K 32 rows x 128B (4 insts, 8 rows each,
  // chunk swz ^(row&7)); V 64 rows x 64B (4 insts, 16 rows each, ^(vrow&3)).
#define WDMA(KB, KL, VL)                                                       \
  _Pragma("unroll") for (int r = 0; r < 4; ++r) {                              \
    int krow = r * 8 + (lane >> 3), kc = lane & 7;                             \
    int kg = kc ^ (krow & 7);                                                  \
    async_load16(Kp + (size_t)((KB) + krow) * 64 + kg * 8, (KL) + r * 512);    \
    int vrow = r * 16 + (lane >> 2), vc = lane & 3;                            \
    int vg = vc ^ (vrow & 3);                                                  \
    async_load16(Vp + (size_t)vrow * SEQ + (KB) + vg * 8, (VL) + r * 512);     \
  }

  // softmax + in-register P^T for one 32-key fragment (R11 math, m=0 case).
  // Source: lane(quad,l15) holds P[k=16t+4*quad+r][q=l15] (t=0..1, r=0..3).
  // Dest PB: lane needs k=8*quad+j (j=0..7), q=l15 -- one B-fragment (K=32).
#define SM32(SRC, PB, G)                                                       \
  {                                                                            \
    float rs = 0.f;                                                            \
    unsigned int wx[2], wy[2];                                                 \
    _Pragma("unroll") for (int t = 0; t < 2; ++t) {                            \
      float p0 = EXP2(SRC[t][0]);                                              \
      float p1 = EXP2(SRC[t][1]);                                              \
      float p2 = EXP2(SRC[t][2]);                                              \
      float p3 = EXP2(SRC[t][3]);                                              \
      rs += (p0 + p1) + (p2 + p3);                                             \
      wx[t] = cvtpk(p0, p1);                                                   \
      wy[t] = cvtpk(p2, p3);                                                   \
    }                                                                          \
    l_i[G] += rs;                                                              \
    unsigned int a = wx[0], c = wx[1], b = wy[0], d = wy[1];                   \
    swap32(a, c); swap16(a, c); /* a -> u32[0], c -> u32[2] */                 \
    swap32(b, d); swap16(b, d); /* b -> u32[1], d -> u32[3] */                 \
    union { short8 s; unsigned int u[4]; } P;                                  \
    P.u[0] = a; P.u[1] = b; P.u[2] = c; P.u[3] = d;                            \
    PB = P.s;                                                                  \
  }

  // Compute one 32-key tile from buffers (KL, VL).
#define FTILE(KL, VL)                                                          \
  {                                                                            \
    f32x4 sT0[2], sT1[2];                                                      \
    __builtin_amdgcn_s_setprio(1);                                             \
    _Pragma("unroll") for (int t = 0; t < 2; ++t) {                            \
      int row = t * 16 + l15;                                                  \
      int c0 = quad ^ (row & 7), c1 = (quad + 4) ^ (row & 7);                  \
      short8 k0 = *(const short8*)((KL) + row * 64 + c0 * 8);                  \
      short8 k1 = *(const short8*)((KL) + row * 64 + c1 * 8);                  \
      sT0[t] = __builtin_amdgcn_mfma_f32_16x16x32_bf16(k0, qf[0][0],           \
               (f32x4){0.f, 0.f, 0.f, 0.f}, 0, 0, 0);                          \
      sT0[t] = __builtin_amdgcn_mfma_f32_16x16x32_bf16(k1, qf[0][1],           \
                                                       sT0[t], 0, 0, 0);       \
      sT1[t] = __builtin_amdgcn_mfma_f32_16x16x32_bf16(k0, qf[1][0],           \
               (f32x4){0.f, 0.f, 0.f, 0.f}, 0, 0, 0);                          \
      sT1[t] = __builtin_amdgcn_mfma_f32_16x16x32_bf16(k1, qf[1][1],           \
                                                       sT1[t], 0, 0, 0);       \
    }                                                                          \
    __builtin_amdgcn_s_setprio(0);                                             \
    short8 pb0, pb1;                                                           \
    SM32(sT0, pb0, 0)                                                          \
    SM32(sT1, pb1, 1)                                                          \
    __builtin_amdgcn_s_setprio(1);                                             \
    _Pragma("unroll") for (int td = 0; td < 4; ++td) {                         \
      int row = td * 16 + l15;                                                 \
      short8 vf = *(const short8*)((VL) + row * 32 +                           \
                                   ((quad ^ (row & 3)) * 8));                  \
      O[0][td] = __builtin_amdgcn_mfma_f32_16x16x32_bf16(vf, pb0,              \
                                                         O[0][td], 0, 0, 0);   \
      O[1][td] = __builtin_amdgcn_mfma_f32_16x16x32_bf16(vf, pb1,              \
                                                         O[1][td], 0, 0, 0);   \
    }                                                                          \
    __builtin_amdgcn_s_setprio(0);                                             \
  }

  WDMA(0, Kl0, Vl0)

  for (int kb = 0; kb < SEQ; kb += 64) {
    // half A: prefetch tile kb+32 -> buf1 (read by this wave last half-B,
    // reads drained), drain tile kb (vmcnt: 16 outstanding -> 8), compute.
    WDMA(kb + 32, Kl1, Vl1)
    __builtin_amdgcn_s_waitcnt(WAITCNT_VM8);
    FTILE(Kl0, Vl0)
    // half B: prefetch tile kb+64 -> buf0 (just consumed above), drain kb+32.
    WDMA((kb + 64) & (SEQ - 1), Kl0, Vl0)
    __builtin_amdgcn_s_waitcnt(WAITCNT_VM8);
    FTILE(Kl1, Vl1)
  }

  // deferred cross-lane reduce: lanes {l15, l15+16, l15+32, l15+48} hold
  // partial row-sums for q=l15; butterfly over bits 4,5 completes it.
#pragma unroll
  for (int g = 0; g < 2; ++g) {
    l_i[g] += __shfl_xor(l_i[g], 16);
    l_i[g] += __shfl_xor(l_i[g], 32);
  }

  const int b_ = bh >> 4, h = bh & 15;
#pragma unroll
  for (int g = 0; g < 2; ++g) {
    const float inv = 1.f / l_i[g];
    unsigned short* orow = Ob + ((size_t)(b_ * SEQ) + qbase + g * 16 + l15) * N_COLS + h * 64;
#pragma unroll
    for (int t = 0; t < 4; ++t) {
      uint2 w;
      w.x = cvtpk(O[g][t][0] * inv, O[g][t][1] * inv);
      w.y = cvtpk(O[g][t][2] * inv, O[g][t][3] * inv);
      *(uint2*)(orow + t * 16 + quad * 4) = w;
    }
  }
#undef WDMA
#undef SM32
#undef FTILE
}

// ---------- output projection: Ob[4096x1024] @ Wo^T -> d_out ----------
__global__ __launch_bounds__(256, 3) void out_gemm_kernel(
    const unsigned short* __restrict__ Ob,
    const unsigned short* __restrict__ Wot,
    void* __restrict__ out,
    const int* __restrict__ flag) {
  __shared__ __align__(16) unsigned short As[2][128 * 32];   // 2 x 8 KB
  __shared__ __align__(16) unsigned short Bs[2][128 * 32];   // 2 x 8 KB
  const int tid = threadIdx.x;
  const int wave = tid >> 6, lane = tid & 63;
  const int quad = lane >> 4, l15 = lane & 15;
  const int wr = wave >> 1, wc = wave & 1;
  const int m0 = blockIdx.x * 128;
  const int n0 = blockIdx.y * 128;
  const int isbf = *flag;

  GEMM_MAIN_LOOP(Ob, Wot, N_COLS)

#pragma unroll
  for (int i = 0; i < 4; ++i) {
#pragma unroll
    for (int j = 0; j < 4; ++j) {
      int mbase = m0 + wr * 64 + i * 16 + quad * 4;
      int n = n0 + wc * 64 + j * 16 + l15;
#pragma unroll
      for (int r = 0; r < 4; ++r) {
        float val = acc[i][j][r];
        if (isbf) ((unsigned short*)out)[(size_t)(mbase + r) * K_DIM + n] = f2bf(val);
        else      ((float*)out)[(size_t)(mbase + r) * K_DIM + n] = val;
      }
    }
  }
}

extern "C" void kernel_launch(void* const* d_in, const int* in_sizes, int n_in,
                              void* d_out, int out_size, void* d_ws, size_t ws_size,
                              hipStream_t stream) {
  const void* x  = d_in[0];
  const void* wq = d_in[1];
  const void* wk = d_in[2];
  const void* wv = d_in[3];
  const void* wo = d_in[4];

  char* ws = (char*)d_ws;
  size_t off = 0;
  int* flag = (int*)(ws + off);                 off += 256;
  unsigned short* xb  = (unsigned short*)(ws + off); off += (size_t)M_ROWS * K_DIM * 2;   // 8 MB
  unsigned short* wqt = (unsigned short*)(ws + off); off += (size_t)K_DIM * N_COLS * 2;   // 2 MB (transposed)
  unsigned short* wkt = (unsigned short*)(ws + off); off += (size_t)K_DIM * N_COLS * 2;
  unsigned short* wvt = (unsigned short*)(ws + off); off += (size_t)K_DIM * N_COLS * 2;
  unsigned short* wot = (unsigned short*)(ws + off); off += (size_t)N_COLS * K_DIM * 2;
  unsigned short* Qb  = (unsigned short*)(ws + off); off += (size_t)M_ROWS * 1024 * 2;  // 8 MB [B,H,S,64]
  unsigned short* Kb  = (unsigned short*)(ws + off); off += (size_t)M_ROWS * 1024 * 2;  // 8 MB
  unsigned short* Vtb = (unsigned short*)(ws + off); off += (size_t)M_ROWS * 1024 * 2;  // 8 MB [B,H,64,S]
  unsigned short* Ob  = (unsigned short*)(ws + off); off += (size_t)M_ROWS * N_COLS * 2; // 8 MB
  (void)ws_size; (void)in_sizes; (void)n_in; (void)out_size;

  detect_kernel<<<1, 256, 0, stream>>>((const unsigned short*)x, flag);

  convert_kernel<<<2048, 256, 0, stream>>>(x, xb, (M_ROWS * K_DIM) / 4, flag);
  convert_wT4_kernel<<<dim3(32, 32, 4), 256, 0, stream>>>(wq, wk, wv, wo,
                                                          wqt, wkt, wvt, wot, flag);

  qkv_gemm_kernel<<<768, 256, 0, stream>>>(xb, wqt, wkt, wvt, Qb, Kb, Vtb);
  flash_kernel<<<512, 256, 0, stream>>>(Qb, Kb, Vtb, Ob);
  out_gemm_kernel<<<dim3(32, 8), 256, 0, stream>>>(Ob, wot, d_out, flag);
}

// Round 12
// 186.744 us; speedup vs baseline: 1.0270x; 1.0270x over previous
//
#include <hip/hip_runtime.h>

// MHA: B=2, S=2048, D=1024, H=16, Kd=64.
// Pipeline: detect dtype -> cast (weights transposed) to bf16 -> QKV GEMM (BK=32
// double-buffered DMA, vmcnt(4)) -> flash attention (double-buffered LDS-DMA,
// vmcnt(8)) -> out GEMM. Raw s_waitcnt immediates survive codegen (R9-proven).
// MFMA layouts (HW-verified): A[m=lane&15][k=(lane>>4)*8+j], B[k=(lane>>4)*8+j][n=lane&15],
// C/D: row=(lane>>4)*4+reg, col=lane&15.
// R10: cvt_pk packing + setprio. R11: permlane P^T exchange (no Plds).
// R12/R14/R17/R20: FAILED flash restructures (retile / 8-wave triple-buffer /
//   direct-L2 @124us / barrier-free per-wave staging @60us). Five independent
//   falsifications: ~51us is the per-wave QK->softmax->PV chain floor at this
//   granularity. R15 g-split kept (+0.5us). Flash frozen ~51.2us.
// R13: XCD pinning flash (bh = gid&31): FETCH 73.8->12.3 MB, -6us. Kept.
// R19: qkv panel-pinned XCD swizzle. Best measured total: 187.19us (R10 round).
// R21: FINAL — exact restore of the R19 best-measured configuration.

typedef __attribute__((ext_vector_type(8))) short short8;
typedef __attribute__((ext_vector_type(4))) float f32x4;

#define M_ROWS 4096   // B*S
#define N_COLS 1024   // H*Kd
#define K_DIM  1024   // D
#define SEQ    2048

// Q pre-scale: (1/sqrt(64)) * log2(e) so softmax exps become exp2.
#define QSCALE 0.18033688011111772f

#if defined(__has_builtin)
#if __has_builtin(__builtin_amdgcn_exp2f)
#define EXP2(x) __builtin_amdgcn_exp2f(x)
#endif
#endif
#ifndef EXP2
#define EXP2(x) exp2f(x)
#endif

// s_waitcnt immediate: vmcnt[3:0]=bits3:0, expcnt=bits6:4 (7=nowait),
// lgkmcnt=bits11:8 (0xF=nowait), vmcnt[5:4]=bits15:14.
#define WAITCNT_VM8 0x0F78
#define WAITCNT_VM4 0x0F74

__device__ inline unsigned short f2bf(float f) {
  unsigned int u = __float_as_uint(f);
  u += 0x7fffu + ((u >> 16) & 1u);   // round-to-nearest-even
  return (unsigned short)(u >> 16);
}

// HW packed f32->bf16 (RNE), 1 VALU op for 2 values (no builtin on gfx950).
__device__ inline unsigned int cvtpk(float lo, float hi) {
  unsigned int r;
  asm("v_cvt_pk_bf16_f32 %0, %1, %2" : "=v"(r) : "v"(lo), "v"(hi));
  return r;
}

// gfx950 cross-lane swaps (VALU, no LDS pipe). Non-volatile: register-only
// dataflow -> compiler may schedule freely.
// permlane32: rows(16-lane) after: a=(a0,a1,b0,b1), b=(a2,a3,b2,b3)
// permlane16: a=(a0,b0,a2,b2), b=(a1,b1,a3,b3)
__device__ inline void swap32(unsigned int& a, unsigned int& b) {
  asm("v_permlane32_swap_b32 %0, %1" : "+v"(a), "+v"(b));
}
__device__ inline void swap16(unsigned int& a, unsigned int& b) {
  asm("v_permlane16_swap_b32 %0, %1" : "+v"(a), "+v"(b));
}

// async global->LDS DMA, 16B per lane. lptr must be wave-uniform (lane i lands
// at lptr + i*16 -- m104/m108); gptr is per-lane.
__device__ inline void async_load16(const unsigned short* gptr, unsigned short* lptr) {
  __builtin_amdgcn_global_load_lds(
      (const __attribute__((address_space(1))) unsigned int*)gptr,
      (__attribute__((address_space(3))) unsigned int*)lptr, 16, 0, 0);
}

// ---------- dtype detector: flag=1 if input buffers are bf16, 0 if f32 ----------
__global__ void detect_kernel(const unsigned short* __restrict__ x, int* __restrict__ flag) {
  __shared__ int bad;
  if (threadIdx.x == 0) bad = 0;
  __syncthreads();
  for (int i = threadIdx.x; i < 1024; i += 256) {
    float f = __uint_as_float((unsigned int)x[i] << 16);
    float a = fabsf(f);
    if (!(a < 1e4f)) atomicOr(&bad, 1);   // catches huge + NaN/Inf -> really f32 data
  }
  __syncthreads();
  if (threadIdx.x == 0) *flag = bad ? 0 : 1;
}

// ---------- cast x (f32 or bf16 per flag) to canonical bf16, layout kept ----------
__global__ void convert_kernel(const void* __restrict__ src, unsigned short* __restrict__ dst,
                               int n4, const int* __restrict__ flag) {
  const int isbf = *flag;
  const int stride = gridDim.x * blockDim.x;
  for (int i = blockIdx.x * blockDim.x + threadIdx.x; i < n4; i += stride) {
    if (isbf) {
      ((uint2*)dst)[i] = ((const uint2*)src)[i];
    } else {
      float4 v = ((const float4*)src)[i];
      ushort4 o;
      o.x = f2bf(v.x); o.y = f2bf(v.y); o.z = f2bf(v.z); o.w = f2bf(v.w);
      ((ushort4*)dst)[i] = o;
    }
  }
}

// ---------- cast + transpose 4 weights [1024][1024] -> W^T bf16 [n][k] ----------
__global__ __launch_bounds__(256) void convert_wT4_kernel(
    const void* __restrict__ s0, const void* __restrict__ s1,
    const void* __restrict__ s2, const void* __restrict__ s3,
    unsigned short* __restrict__ d0, unsigned short* __restrict__ d1,
    unsigned short* __restrict__ d2, unsigned short* __restrict__ d3,
    const int* __restrict__ flag) {
  __shared__ unsigned short t[32][33];
  const int z = blockIdx.z;
  const void* src = (z == 0) ? s0 : (z == 1) ? s1 : (z == 2) ? s2 : s3;
  unsigned short* dst = (z == 0) ? d0 : (z == 1) ? d1 : (z == 2) ? d2 : d3;
  const int tid = threadIdx.x;
  const int r0 = blockIdx.y * 32, c0 = blockIdx.x * 32;   // r0: k rows, c0: n cols
  const int kr = tid >> 3, nc = (tid & 7) * 4;
  if (*flag) {
    const unsigned short* W = (const unsigned short*)src;
    uint2 v = *(const uint2*)(W + (size_t)(r0 + kr) * K_DIM + c0 + nc);
    t[kr][nc] = v.x & 0xffff; t[kr][nc + 1] = v.x >> 16;
    t[kr][nc + 2] = v.y & 0xffff; t[kr][nc + 3] = v.y >> 16;
  } else {
    const float* W = (const float*)src;
    float4 v = *(const float4*)(W + (size_t)(r0 + kr) * K_DIM + c0 + nc);
    t[kr][nc] = f2bf(v.x); t[kr][nc + 1] = f2bf(v.y);
    t[kr][nc + 2] = f2bf(v.z); t[kr][nc + 3] = f2bf(v.w);
  }
  __syncthreads();
  const int nr = tid >> 3, kc = (tid & 7) * 4;
  uint2 w;
  w.x = (unsigned int)t[kc][nr] | ((unsigned int)t[kc + 1][nr] << 16);
  w.y = (unsigned int)t[kc + 2][nr] | ((unsigned int)t[kc + 3][nr] << 16);
  *(uint2*)(dst + (size_t)(c0 + nr) * K_DIM + r0 + kc) = w;
}

// ---------- 128x128xBK32 GEMM core, double-buffered DMA + vmcnt(4) ----------
// (R9-proven form.) Per K-iter: prefetch next tile's 4 DMAs FIRST, wait
// vmcnt(4), barrier, 8 ds_read_b128 + 16 MFMA, barrier. XOR swizzle
// c = g ^ ((row^(row>>2))&3) -> 2 lanes/bank reads (free).
#define GEMM_DMA(Aptr, Bptr, KTOT, KB, BUF)                                       \
  _Pragma("unroll") for (int r = 0; r < 2; ++r) {                                 \
    int s = r * 256 + wave * 64 + lane;                                           \
    int row = s >> 2, c = s & 3;                                                  \
    int g = c ^ ((row ^ (row >> 2)) & 3);                                         \
    async_load16((Aptr) + (size_t)(m0 + row) * (KTOT) + (KB) + g * 8,             \
                 &As[BUF][(size_t)(r * 256 + wave * 64) * 8]);                    \
    async_load16((Bptr) + (size_t)(n0 + row) * (KTOT) + (KB) + g * 8,             \
                 &Bs[BUF][(size_t)(r * 256 + wave * 64) * 8]);                    \
  }

#define GEMM_MAIN_LOOP(Aptr, Bptr, KTOT)                                          \
  f32x4 acc[4][4];                                                                \
  _Pragma("unroll") for (int i = 0; i < 4; ++i)                                   \
  _Pragma("unroll") for (int j = 0; j < 4; ++j)                                   \
      acc[i][j] = (f32x4){0.f, 0.f, 0.f, 0.f};                                    \
  const int xr = (l15 ^ (l15 >> 2)) & 3;                                          \
  GEMM_DMA(Aptr, Bptr, KTOT, 0, 0)                                                \
  for (int kb = 0; kb < (KTOT); kb += 32) {                                       \
    const int pp = (kb >> 5) & 1;                                                 \
    const int kbn = (kb + 32) & ((KTOT) - 1);                                     \
    GEMM_DMA(Aptr, Bptr, KTOT, kbn, pp ^ 1)                                       \
    __builtin_amdgcn_s_waitcnt(WAITCNT_VM4);                                      \
    __syncthreads();                                                              \
    short8 am[4], bn[4];                                                          \
    _Pragma("unroll") for (int i = 0; i < 4; ++i) {                               \
      int arow = wr * 64 + i * 16 + l15;                                          \
      int brow = wc * 64 + i * 16 + l15;                                          \
      int cc = quad ^ xr;                                                         \
      am[i] = *(const short8*)(&As[pp][arow * 32 + cc * 8]);                      \
      bn[i] = *(const short8*)(&Bs[pp][brow * 32 + cc * 8]);                      \
    }                                                                             \
    _Pragma("unroll") for (int i = 0; i < 4; ++i)                                 \
    _Pragma("unroll") for (int j = 0; j < 4; ++j)                                 \
        acc[i][j] = __builtin_amdgcn_mfma_f32_16x16x32_bf16(am[i], bn[j],         \
                                                            acc[i][j], 0, 0, 0); \
    __syncthreads();                                                              \
  }

// ---------- fused QKV projection: X[4096x1024] @ W^T -> Q/K/V ----------
// R19: 1-D grid of 768, panel-pinned XCD decode: y = gid&7 (XCD = gid%8),
// wsel = (gid>>3)/32, x = (gid>>3)&31. All 96 blocks on XCD r consume weight
// cols [r*128,(r+1)*128) of Wq/Wk/Wv -> 768 KB B working set, L2-resident.
// 3 blocks/CU (launch_bounds(256,3)), zero tail. Body unchanged (proven).
__global__ __launch_bounds__(256, 3) void qkv_gemm_kernel(
    const unsigned short* __restrict__ Xb,
    const unsigned short* __restrict__ Wqt,
    const unsigned short* __restrict__ Wkt,
    const unsigned short* __restrict__ Wvt,
    unsigned short* __restrict__ Qb,
    unsigned short* __restrict__ Kb,
    unsigned short* __restrict__ Vt) {
  __shared__ __align__(16) unsigned short As[2][128 * 32];   // 2 x 8 KB
  __shared__ __align__(16) unsigned short Bs[2][128 * 32];   // 2 x 8 KB
  const int tid = threadIdx.x;
  const int wave = tid >> 6, lane = tid & 63;
  const int quad = lane >> 4, l15 = lane & 15;
  const int wr = wave >> 1, wc = wave & 1;
  const int gid = blockIdx.x;
  const int ny = gid & 7;            // XCD-pinned n-panel
  const int q = gid >> 3;
  const int wsel = q >> 5;           // 0..2
  const int m0 = (q & 31) * 128;
  const int n0 = ny * 128;
  const unsigned short* __restrict__ Bt =
      (wsel == 0) ? Wqt : ((wsel == 1) ? Wkt : Wvt);

  GEMM_MAIN_LOOP(Xb, Bt, K_DIM)

#pragma unroll
  for (int i = 0; i < 4; ++i) {
#pragma unroll
    for (int j = 0; j < 4; ++j) {
      int mbase = m0 + wr * 64 + i * 16 + quad * 4;
      int n = n0 + wc * 64 + j * 16 + l15;
      int h = n >> 6, d = n & 63;
      if (wsel == 2) {
        int b_ = mbase >> 11, s = mbase & 2047;
        uint2 w;
        w.x = cvtpk(acc[i][j][0], acc[i][j][1]);
        w.y = cvtpk(acc[i][j][2], acc[i][j][3]);
        *(uint2*)(Vt + ((size_t)(b_ * 16 + h) * 64 + d) * SEQ + s) = w;
      } else {
#pragma unroll
        for (int r = 0; r < 4; ++r) {
          int m = mbase + r;
          int b_ = m >> 11, s = m & 2047;
          float val = acc[i][j][r];
          if (wsel == 0)
            Qb[((size_t)(b_ * 16 + h) * SEQ + s) * 64 + d] = f2bf(val * QSCALE);
          else
            Kb[((size_t)(b_ * 16 + h) * SEQ + s) * 64 + d] = f2bf(val);
        }
      }
    }
  }
}

// ---------- flash attention: double-buffered DMA, 128q/4-wave, 128-key tiles ----------
// R13 skeleton + R15 g-split pipeline. FROZEN (best measured ~51.0-51.4us).
__global__ __launch_bounds__(256, 2) void flash_kernel(
    const unsigned short* __restrict__ Qb,
    const unsigned short* __restrict__ Kb,
    const unsigned short* __restrict__ Vt,
    unsigned short* __restrict__ Ob) {
  __shared__ __align__(16) unsigned short Klds[2][128 * 64];   // [buf][key][d] swz, 32 KB
  __shared__ __align__(16) unsigned short Vlds[2][64 * 128];   // [buf][d][key] swz, 32 KB
  const int tid = threadIdx.x;
  const int wave = tid >> 6, lane = tid & 63;
  const int quad = lane >> 4, l15 = lane & 15;
  const int gid = blockIdx.x;
  const int bh = gid & 31;          // XCD = gid % 8 = bh % 8: head pinned to XCD
  const int qidx = gid >> 5;        // 16 q-chunks per head
  const int qbase = qidx * 128 + wave * 32;

  const unsigned short* __restrict__ Qp = Qb + (size_t)bh * SEQ * 64;
  const unsigned short* __restrict__ Kp = Kb + (size_t)bh * SEQ * 64;
  const unsigned short* __restrict__ Vp = Vt + (size_t)bh * 64 * SEQ;

  short8 qf[2][2];
#pragma unroll
  for (int g = 0; g < 2; ++g)
#pragma unroll
    for (int h = 0; h < 2; ++h)
      qf[g][h] = *(const short8*)(Qp + (size_t)(qbase + g * 16 + l15) * 64 + h * 32 + quad * 8);

  f32x4 O[2][4];
#pragma unroll
  for (int g = 0; g < 2; ++g)
#pragma unroll
    for (int t = 0; t < 4; ++t) O[g][t] = (f32x4){0.f, 0.f, 0.f, 0.f};
  float l_i[2] = {0.f, 0.f};   // per-lane partials; cross-lane reduce at epilogue

#define FLASH_DMA(KB, BUF)                                                     \
  _Pragma("unroll") for (int r = 0; r < 4; ++r) {                              \
    int s = r * 256 + tid;                                                     \
    int krow = s >> 3, kc = s & 7;                                             \
    int kg = kc ^ (krow & 7);                                                  \
    async_load16(Kp + (size_t)((KB) + krow) * 64 + kg * 8,                     \
                 &Klds[BUF][(size_t)(r * 256 + wave * 64) * 8]);               \
    int vrow = s >> 4, vc = s & 15;                                            \
    int vg = vc ^ (vrow & 15);                                                 \
    async_load16(Vp + (size_t)vrow * SEQ + (KB) + vg * 8,                      \
                 &Vlds[BUF][(size_t)(r * 256 + wave * 64) * 8]);               \
  }

  // QK fragment read for one t, shared address math.
#define QK_READ(t)                                                             \
  int row = (t) * 16 + l15;                                                    \
  int c0 = quad ^ (row & 7), c1 = (quad + 4) ^ (row & 7);                      \
  short8 k0 = *(const short8*)(&Klds[p][row * 64 + c0 * 8]);                   \
  short8 k1 = *(const short8*)(&Klds[p][row * 64 + c1 * 8]);

  // softmax + in-register P^T redistribution for one g.
  // Source: lane(quad,l15) holds P[k=16t+4*quad+r][q=l15] (r=0..3).
  // Dest pb[m]: lane needs k=32m+8*quad+j (j=0..7), q=l15 -- B-fragment.
#define SOFTMAX_G(SRC, PB, G)                                                  \
  {                                                                            \
    float rs = 0.f;                                                            \
    unsigned int wx[8], wy[8];                                                 \
    _Pragma("unroll") for (int t = 0; t < 8; ++t) {                            \
      float p0 = EXP2(SRC[t][0]);                                              \
      float p1 = EXP2(SRC[t][1]);                                              \
      float p2 = EXP2(SRC[t][2]);                                              \
      float p3 = EXP2(SRC[t][3]);                                              \
      rs += (p0 + p1) + (p2 + p3);                                             \
      wx[t] = cvtpk(p0, p1);                                                   \
      wy[t] = cvtpk(p2, p3);                                                   \
    }                                                                          \
    l_i[G] += rs;                                                              \
    _Pragma("unroll") for (int m = 0; m < 4; ++m) {                            \
      unsigned int a = wx[2 * m], c = wx[2 * m + 1];                           \
      unsigned int b = wy[2 * m], d = wy[2 * m + 1];                           \
      swap32(a, c); swap16(a, c); /* a -> u32[0], c -> u32[2] */               \
      swap32(b, d); swap16(b, d); /* b -> u32[1], d -> u32[3] */               \
      union { short8 s; unsigned int u[4]; } P;                                \
      P.u[0] = a; P.u[1] = b; P.u[2] = c; P.u[3] = d;                          \
      PB[m] = P.s;                                                             \
    }                                                                          \
  }

#define PV_G(PB, G)                                                            \
  _Pragma("unroll") for (int td = 0; td < 4; ++td) {                           \
    int vrow = td * 16 + l15;                                                  \
    _Pragma("unroll") for (int m = 0; m < 4; ++m) {                            \
      short8 vf = *(const short8*)(&Vlds[p][vrow * 128 +                       \
                                           (((m * 4 + quad) ^ l15) * 8)]);     \
      O[G][td] = __builtin_amdgcn_mfma_f32_16x16x32_bf16(vf, PB[m],            \
                                                         O[G][td], 0, 0, 0);   \
    }                                                                          \
  }

  FLASH_DMA(0, 0)

  for (int kb = 0; kb < SEQ; kb += 128) {
    const int p = (kb >> 7) & 1;
    const int kbn = (kb + 128) & (SEQ - 1);
    FLASH_DMA(kbn, p ^ 1)
    __builtin_amdgcn_s_waitcnt(WAITCNT_VM8);
    __syncthreads();

    // ---- stage 1: QK(g0) -- pure MFMA cluster ----
    f32x4 sT0[8], sT1[8];
    __builtin_amdgcn_s_setprio(1);
#pragma unroll
    for (int t = 0; t < 8; ++t) {
      QK_READ(t)
      sT0[t] = __builtin_amdgcn_mfma_f32_16x16x32_bf16(k0, qf[0][0],
               (f32x4){0.f, 0.f, 0.f, 0.f}, 0, 0, 0);
      sT0[t] = __builtin_amdgcn_mfma_f32_16x16x32_bf16(k1, qf[0][1], sT0[t], 0, 0, 0);
    }
    __builtin_amdgcn_s_setprio(0);

    // ---- stage 2: QK(g1) [MFMA] || sm(g0) [VALU] -- independent, adjacent ----
#pragma unroll
    for (int t = 0; t < 8; ++t) {
      QK_READ(t)
      sT1[t] = __builtin_amdgcn_mfma_f32_16x16x32_bf16(k0, qf[1][0],
               (f32x4){0.f, 0.f, 0.f, 0.f}, 0, 0, 0);
      sT1[t] = __builtin_amdgcn_mfma_f32_16x16x32_bf16(k1, qf[1][1], sT1[t], 0, 0, 0);
    }
    short8 pb0[4];
    SOFTMAX_G(sT0, pb0, 0)

    // ---- stage 3: PV(g0) [MFMA] || sm(g1) [VALU] -- independent, adjacent ----
    PV_G(pb0, 0)
    short8 pb1[4];
    SOFTMAX_G(sT1, pb1, 1)

    // ---- stage 4: PV(g1) ----
    PV_G(pb1, 1)

    __syncthreads();
  }

  // deferred cross-lane reduce: lanes {l15, l15+16, l15+32, l15+48} hold
  // partial row-sums for q=l15; butterfly over bits 4,5 completes it.
#pragma unroll
  for (int g = 0; g < 2; ++g) {
    l_i[g] += __shfl_xor(l_i[g], 16);
    l_i[g] += __shfl_xor(l_i[g], 32);
  }

  const int b_ = bh >> 4, h = bh & 15;
#pragma unroll
  for (int g = 0; g < 2; ++g) {
    const float inv = 1.f / l_i[g];
    unsigned short* orow = Ob + ((size_t)(b_ * SEQ) + qbase + g * 16 + l15) * N_COLS + h * 64;
#pragma unroll
    for (int t = 0; t < 4; ++t) {
      uint2 w;
      w.x = cvtpk(O[g][t][0] * inv, O[g][t][1] * inv);
      w.y = cvtpk(O[g][t][2] * inv, O[g][t][3] * inv);
      *(uint2*)(orow + t * 16 + quad * 4) = w;
    }
  }
#undef FLASH_DMA
#undef QK_READ
#undef SOFTMAX_G
#undef PV_G
}

// ---------- output projection: Ob[4096x1024] @ Wo^T -> d_out ----------
__global__ __launch_bounds__(256, 3) void out_gemm_kernel(
    const unsigned short* __restrict__ Ob,
    const unsigned short* __restrict__ Wot,
    void* __restrict__ out,
    const int* __restrict__ flag) {
  __shared__ __align__(16) unsigned short As[2][128 * 32];   // 2 x 8 KB
  __shared__ __align__(16) unsigned short Bs[2][128 * 32];   // 2 x 8 KB
  const int tid = threadIdx.x;
  const int wave = tid >> 6, lane = tid & 63;
  const int quad = lane >> 4, l15 = lane & 15;
  const int wr = wave >> 1, wc = wave & 1;
  const int m0 = blockIdx.x * 128;
  const int n0 = blockIdx.y * 128;
  const int isbf = *flag;

  GEMM_MAIN_LOOP(Ob, Wot, N_COLS)

#pragma unroll
  for (int i = 0; i < 4; ++i) {
#pragma unroll
    for (int j = 0; j < 4; ++j) {
      int mbase = m0 + wr * 64 + i * 16 + quad * 4;
      int n = n0 + wc * 64 + j * 16 + l15;
#pragma unroll
      for (int r = 0; r < 4; ++r) {
        float val = acc[i][j][r];
        if (isbf) ((unsigned short*)out)[(size_t)(mbase + r) * K_DIM + n] = f2bf(val);
        else      ((float*)out)[(size_t)(mbase + r) * K_DIM + n] = val;
      }
    }
  }
}

extern "C" void kernel_launch(void* const* d_in, const int* in_sizes, int n_in,
                              void* d_out, int out_size, void* d_ws, size_t ws_size,
                              hipStream_t stream) {
  const void* x  = d_in[0];
  const void* wq = d_in[1];
  const void* wk = d_in[2];
  const void* wv = d_in[3];
  const void* wo = d_in[4];

  char* ws = (char*)d_ws;
  size_t off = 0;
  int* flag = (int*)(ws + off);                 off += 256;
  unsigned short* xb  = (unsigned short*)(ws + off); off += (size_t)M_ROWS * K_DIM * 2;   // 8 MB
  unsigned short* wqt = (unsigned short*)(ws + off); off += (size_t)K_DIM * N_COLS * 2;   // 2 MB (transposed)
  unsigned short* wkt = (unsigned short*)(ws + off); off += (size_t)K_DIM * N_COLS * 2;
  unsigned short* wvt = (unsigned short*)(ws + off); off += (size_t)K_DIM * N_COLS * 2;
  unsigned short* wot = (unsigned short*)(ws + off); off += (size_t)N_COLS * K_DIM * 2;
  unsigned short* Qb  = (unsigned short*)(ws + off); off += (size_t)M_ROWS * 1024 * 2;  // 8 MB [B,H,S,64]
  unsigned short* Kb  = (unsigned short*)(ws + off); off += (size_t)M_ROWS * 1024 * 2;  // 8 MB
  unsigned short* Vtb = (unsigned short*)(ws + off); off += (size_t)M_ROWS * 1024 * 2;  // 8 MB [B,H,64,S]
  unsigned short* Ob  = (unsigned short*)(ws + off); off += (size_t)M_ROWS * N_COLS * 2; // 8 MB
  (void)ws_size; (void)in_sizes; (void)n_in; (void)out_size;

  detect_kernel<<<1, 256, 0, stream>>>((const unsigned short*)x, flag);

  convert_kernel<<<2048, 256, 0, stream>>>(x, xb, (M_ROWS * K_DIM) / 4, flag);
  convert_wT4_kernel<<<dim3(32, 32, 4), 256, 0, stream>>>(wq, wk, wv, wo,
                                                          wqt, wkt, wvt, wot, flag);

  qkv_gemm_kernel<<<768, 256, 0, stream>>>(xb, wqt, wkt, wvt, Qb, Kb, Vtb);
  flash_kernel<<<512, 256, 0, stream>>>(Qb, Kb, Vtb, Ob);
  out_gemm_kernel<<<dim3(32, 8), 256, 0, stream>>>(Ob, wot, d_out, flag);
}